// Round 7
// baseline (613.839 us; speedup 1.0000x reference)
//
#include <hip/hip_runtime.h>
#include <utility>
#include <cstddef>

// ---------------- compile-time Ivanic-Ruedenberg tables ----------------

struct Term { int o; int r; int a; float c; };
struct LTable { int n; Term t[1024]; };

constexpr double csqrt(double x) {
    if (x <= 0.0) return 0.0;
    double g = x < 1.0 ? 1.0 : x;
    for (int i = 0; i < 50; ++i) g = 0.5 * (g + x / g);
    return g;
}
constexpr int cabs_i(int x) { return x < 0 ? -x : x; }
constexpr int cmax_i(int a, int b) { return a > b ? a : b; }

constexpr void add_p(LTable& T, int o, double scale, int i, int a, int b, int l) {
    int lp = l - 1;
    int np = 2 * lp + 1;
    int row = i + 1;
    if (b == l) {
        T.t[T.n++] = Term{o, row * 3 + 2, (a + lp) * np + 2 * lp, (float)scale};
        T.t[T.n++] = Term{o, row * 3 + 0, (a + lp) * np + 0,      (float)(-scale)};
    } else if (b == -l) {
        T.t[T.n++] = Term{o, row * 3 + 2, (a + lp) * np + 0,      (float)scale};
        T.t[T.n++] = Term{o, row * 3 + 0, (a + lp) * np + 2 * lp, (float)scale};
    } else {
        T.t[T.n++] = Term{o, row * 3 + 1, (a + lp) * np + (b + lp), (float)scale};
    }
}

constexpr LTable ru_table(int l) {
    LTable T{};
    int n = 2 * l + 1;
    for (int m = -l; m <= l; ++m) {
        for (int mp = -l; mp <= l; ++mp) {
            double denom = (cabs_i(mp) == l) ? (double)((2 * l) * (2 * l - 1))
                                             : (double)((l + mp) * (l - mp));
            double d0 = (m == 0) ? 1.0 : 0.0;
            double u = csqrt((double)((l + m) * (l - m)) / denom);
            double v = 0.5 * csqrt((1.0 + d0) * (l + cabs_i(m) - 1) * (l + cabs_i(m)) / denom)
                       * (1.0 - 2.0 * d0);
            double w = -0.5 * csqrt((double)cmax_i(l - cabs_i(m) - 1, 0) * (l - cabs_i(m)) / denom)
                       * (1.0 - d0);
            int o = (m + l) * n + (mp + l);
            if (u != 0.0) add_p(T, o, u, 0, m, mp, l);
            if (v != 0.0) {
                if (m == 0) {
                    add_p(T, o, v, 1, 1, mp, l);
                    add_p(T, o, v, -1, -1, mp, l);
                } else if (m > 0) {
                    double s = (m == 1) ? csqrt(2.0) : 1.0;
                    add_p(T, o, v * s, 1, m - 1, mp, l);
                    if (m != 1) add_p(T, o, -v, -1, -m + 1, mp, l);
                } else {
                    if (m != -1) add_p(T, o, v, 1, m + 1, mp, l);
                    double s = (m == -1) ? csqrt(2.0) : 1.0;
                    add_p(T, o, v * s, -1, -m - 1, mp, l);
                }
            }
            if (w != 0.0) {
                if (m > 0) {
                    add_p(T, o, w, 1, m + 1, mp, l);
                    add_p(T, o, w, -1, -m - 1, mp, l);
                } else {
                    add_p(T, o, w, 1, m - 1, mp, l);
                    add_p(T, o, -w, -1, -m + 1, mp, l);
                }
            }
        }
    }
    return T;
}

inline constexpr LTable T2 = ru_table(2);
inline constexpr LTable T3 = ru_table(3);
inline constexpr LTable T4 = ru_table(4);

// terms for a given output entry are contiguous by construction (m-major, mp-minor)
template<const LTable& T>
constexpr int er_start(int e) {
    for (int i = 0; i < T.n; ++i) if (T.t[i].o == e) return i;
    return 0;
}
template<const LTable& T>
constexpr int er_cnt(int e) {
    int c = 0;
    for (int i = 0; i < T.n; ++i) if (T.t[i].o == e) ++c;
    return c;
}

// sum of terms, all operands in register arrays (compile-time indices only)
template<const LTable& T, int S, size_t... K>
__device__ __forceinline__ float sum_terms(const float* __restrict__ R1,
                                           const float* __restrict__ P,
                                           std::index_sequence<K...>) {
    float a = 0.0f;
    ((a = fmaf(T.t[S + (int)K].c, R1[T.t[S + (int)K].r] * P[T.t[S + (int)K].a], a)), ...);
    return a;
}

// build a whole level into a register array (no LDS involvement)
template<const LTable& T, size_t... E>
__device__ __forceinline__ void level_reg(const float* __restrict__ R1,
                                          const float* __restrict__ P,
                                          float* __restrict__ D,
                                          std::index_sequence<E...>) {
    ((D[(int)E] = sum_terms<T, er_start<T>((int)E)>(
          R1, P, std::make_index_sequence<er_cnt<T>((int)E)>{})), ...);
}

// dump one level's register array into the 25x25 image row (imm offsets)
template<int l, size_t... E>
__device__ __forceinline__ void dump_level(const float* __restrict__ D,
                                           float* __restrict__ row,
                                           std::index_sequence<E...>) {
    ((row[(l * l + (int)E / (2 * l + 1)) * 25 + (l * l + (int)E % (2 * l + 1))]
          = D[(int)E]), ...);
}

typedef float v4f __attribute__((ext_vector_type(4)));

// ---------------- fused kernel ----------------
// Round-7: WAVE-PRIVATE 8-POINT IMAGE, BARRIER-FREE, L2-ROUTED COPIES.
// Evidence chain: R6 showed scatter is the critical path and barriers
// serialize it; R3 validated the barrier-free wave-private pattern for
// correctness but died on 256B misaligned NONTEMPORAL stores (no L2
// combining -> partial-line RMW, 1.84 TB/s); R5 + the fill kernel prove
// plain stores reach 6.3 TB/s via L2 write-combining at tiny occupancy.
// This kernel = R3's autonomy + R0's contiguous full-line copy pattern.
//
// Block 256 = 4 waves; each wave owns 64 points (lane = point) and a
// PRIVATE 8x625 image (20,000 B; 4 waves = 80,000 B -> 2 blocks/CU,
// 8 independent wave-pipelines/CU). Every lane computes R1,D2,D3,D4 into
// registers ONCE (164 floats; __launch_bounds__(256,2) caps at 256 VGPR).
// Then 8 rounds: 8 owner lanes dump their rows (165 pure ds_writes from
// regs, compile-time offsets, banks (17p+E)%32 conflict-free) ->
// wave-internal s_waitcnt lgkmcnt(0) (NO s_barrier) -> all 64 lanes copy
// the image as a contiguous 16B-aligned v4f stream with PLAIN stores
// (L2-combined full lines) -> lgkmcnt(0) closes the WAR for the next dump.
// Zero-structure slots written once at wave start, never touched again.

__global__ __launch_bounds__(256, 2)
void wigner_fused_kernel(const float* __restrict__ xyz, float* __restrict__ out, int Ntot) {
    __shared__ __align__(16) float lds[4][8 * 625];   // 80,000 B

    const int t = threadIdx.x;
    const int w = t >> 6;
    const int lane = t & 63;
    float* __restrict__ strip = lds[w];

    const long long wbase = (long long)blockIdx.x * 256 + (long long)w * 64;
    if (wbase >= Ntot) return;   // wave-uniform; no barriers in this kernel
    const long long pt = wbase + lane;

    float x = 0.0f, y = 0.0f, z = 1.0f;
    if (pt < Ntot) {
        x = xyz[3 * pt + 0];
        y = xyz[3 * pt + 1];
        z = xyz[3 * pt + 2];
    }

    // trig without trig: ct = vz (clipped), st = sqrt(1-ct^2), cp/sp from x,y
    const float r2 = x * x + y * y + z * z;
    const float rinv = rsqrtf(fmaxf(r2, 1e-24f));
    const float ct = fminf(fmaxf(z * rinv, -1.0f), 1.0f);
    const float st = sqrtf(fmaxf(1.0f - ct * ct, 0.0f));
    const float rxy2 = x * x + y * y;
    float cp = 1.0f, sp = 0.0f;
    if (rxy2 > 0.0f) {
        const float ri = rsqrtf(rxy2);
        cp = x * ri;
        sp = y * ri;
    }

    // R1 in real-SH l=1 basis order (y,z,x), row-major 3x3
    const float R1[9] = {cp,      0.0f, -sp,
                         st * sp, ct,   st * cp,
                         ct * sp, -st,  ct * cp};

    // full D in registers, once per lane (no recompute in the dump rounds)
    float D2[25];
    level_reg<T2>(R1, R1, D2, std::make_index_sequence<25>{});
    float D3[49];
    level_reg<T3>(R1, D2, D3, std::make_index_sequence<49>{});
    float D4[81];
    level_reg<T4>(R1, D3, D4, std::make_index_sequence<81>{});

    // zero the wave's image once (structural-zero slots never rewritten)
    {
        v4f* b4 = (v4f*)strip;
        const v4f z4 = {0.0f, 0.0f, 0.0f, 0.0f};
#pragma unroll 4
        for (int k = lane; k < 1250; k += 64) b4[k] = z4;
    }
    asm volatile("s_waitcnt lgkmcnt(0)" ::: "memory");  // zeros visible wave-wide

#pragma unroll 1
    for (int r = 0; r < 8; ++r) {
        const long long rbase = wbase + (long long)r * 8;
        if (rbase >= Ntot) break;   // wave-uniform

        // dump: the 8 owner lanes write their full row from registers
        if ((lane >> 3) == r && pt < Ntot) {
            float* __restrict__ row = strip + (lane & 7) * 625;
            row[0] = 1.0f;
            dump_level<1>(R1, row, std::make_index_sequence<9>{});
            dump_level<2>(D2, row, std::make_index_sequence<25>{});
            dump_level<3>(D3, row, std::make_index_sequence<49>{});
            dump_level<4>(D4, row, std::make_index_sequence<81>{});
        }
        // wave-internal fence: dumps visible to all lanes of this wave
        asm volatile("s_waitcnt lgkmcnt(0)" ::: "memory");

        // copy: 20,000 B contiguous, plain 16B stores (L2 write-combining)
        const int valid = (int)(Ntot - rbase < 8 ? Ntot - rbase : 8);
        if (valid == 8) {
            const v4f* __restrict__ src = (const v4f*)strip;
            v4f* __restrict__ dst = (v4f*)(out + rbase * 625);
#pragma unroll 4
            for (int k = lane; k < 1250; k += 64) dst[k] = src[k];
        } else {
            const int vf = valid * 625;
            float* __restrict__ dstf = out + rbase * 625;
            for (int k = lane; k < vf; k += 64) dstf[k] = strip[k];
        }
        // copy ds_reads retired before next round's dump overwrites (WAR)
        asm volatile("s_waitcnt lgkmcnt(0)" ::: "memory");
    }
}

extern "C" void kernel_launch(void* const* d_in, const int* in_sizes, int n_in,
                              void* d_out, int out_size, void* d_ws, size_t ws_size,
                              hipStream_t stream) {
    const float* xyz = (const float*)d_in[0];
    float* out = (float*)d_out;
    const int N = in_sizes[0] / 3;
    const int blocks = (N + 255) / 256;
    hipLaunchKernelGGL(wigner_fused_kernel, dim3(blocks), dim3(256), 0, stream,
                       xyz, out, N);
}